// Round 1
// baseline (681.279 us; speedup 1.0000x reference)
//
#include <hip/hip_runtime.h>
#include <math.h>

#define B_ 32
#define L_ 2049
#define S_ 2048
#define E_ 1024
#define H_ 16
#define NT_ 8
#define STILE 256
#define EC 32            // e-chunk, phase 1
#define SC 8             // s-chunk, phase 2
#define NCH1 (E_/EC)     // 32
#define NCH2 (STILE/SC)  // 32

// workspace layout (float offsets)
#define OFF_Q     0
#define OFF_T     (OFF_Q + B_*E_)                 // t = 0.125 * q_h @ Wk_h, (B,H,E)
#define OFF_QBK   (OFF_T + B_*H_*E_)              // 0.125 * q_h . bk_h, (B,H)
#define OFF_M     (OFF_QBK + B_*H_)               // per-tile max (B,NT,H)
#define OFF_L     (OFF_M + B_*NT_*H_)             // per-tile expsum (B,NT,H)
#define OFF_U     (OFF_L + B_*NT_*H_)             // combined u (B,H,E)
#define OFF_ATTN  (OFF_U + B_*H_*E_)              // (B,E)
#define OFF_Y     (OFF_ATTN + B_*E_)              // pre-LN y (B,E)
#define OFF_UP    (OFF_Y + B_*E_)                 // partial u (B,NT,H,E)

// ---------------------------------------------------------------- K1a: q = cls @ Wq^T + bq
__global__ __launch_bounds__(256) void k_qproj(const float* __restrict__ x,
                                               const float* __restrict__ Wq,
                                               const float* __restrict__ bq,
                                               float* __restrict__ ws) {
    __shared__ float cls[8 * 1024];
    const int bg = blockIdx.x;        // 0..3 -> 8 batches each
    const int j0 = blockIdx.y * 128;  // 8 j-slices
    const int tid = threadIdx.x;
    #pragma unroll
    for (int k = 0; k < 8; ++k) {
        int idx4 = k * 256 + tid;
        int bb = idx4 >> 8, e4 = idx4 & 255;
        float4 v = *(const float4*)(x + (size_t)((bg * 8 + bb) * L_) * E_ + 4 * e4);
        *(float4*)(cls + bb * 1024 + 4 * e4) = v;
    }
    __syncthreads();
    const int jj = tid & 127, bh = tid >> 7;
    const int j = j0 + jj;
    float a0 = 0.f, a1 = 0.f, a2 = 0.f, a3 = 0.f;
    const float4* wrow = (const float4*)(Wq + (size_t)j * E_);
    const float* c0 = cls + (bh * 4 + 0) * 1024;
    const float* c1 = cls + (bh * 4 + 1) * 1024;
    const float* c2 = cls + (bh * 4 + 2) * 1024;
    const float* c3 = cls + (bh * 4 + 3) * 1024;
    for (int e4 = 0; e4 < 256; ++e4) {
        float4 w = wrow[e4];
        int e = 4 * e4;
        a0 += w.x * c0[e] + w.y * c0[e + 1] + w.z * c0[e + 2] + w.w * c0[e + 3];
        a1 += w.x * c1[e] + w.y * c1[e + 1] + w.z * c1[e + 2] + w.w * c1[e + 3];
        a2 += w.x * c2[e] + w.y * c2[e + 1] + w.z * c2[e + 2] + w.w * c2[e + 3];
        a3 += w.x * c3[e] + w.y * c3[e + 1] + w.z * c3[e + 2] + w.w * c3[e + 3];
    }
    float bqv = bq[j];
    float* q = ws + OFF_Q;
    q[(bg * 8 + bh * 4 + 0) * E_ + j] = a0 + bqv;
    q[(bg * 8 + bh * 4 + 1) * E_ + j] = a1 + bqv;
    q[(bg * 8 + bh * 4 + 2) * E_ + j] = a2 + bqv;
    q[(bg * 8 + bh * 4 + 3) * E_ + j] = a3 + bqv;
}

// ---------------------------------------------------------------- K1b: t = 0.125*q_h@Wk_h ; qbk
__global__ __launch_bounds__(512) void k_tproj(const float* __restrict__ Wk,
                                               const float* __restrict__ bk,
                                               float* __restrict__ ws) {
    __shared__ float qs[64 * 33];  // [d][b] padded
    const int h = blockIdx.x, tid = threadIdx.x;
    const float* q = ws + OFF_Q;
    #pragma unroll
    for (int k = 0; k < 4; ++k) {
        int idx = k * 512 + tid;  // 2048 = 32b * 64d
        int b = idx >> 6, d = idx & 63;
        qs[d * 33 + b] = q[b * E_ + 64 * h + d];
    }
    __syncthreads();
    float accx[32], accy[32];
    #pragma unroll
    for (int b = 0; b < 32; ++b) { accx[b] = 0.f; accy[b] = 0.f; }
    for (int d = 0; d < 64; ++d) {
        float2 w = *(const float2*)(Wk + (size_t)(64 * h + d) * E_ + 2 * tid);
        #pragma unroll
        for (int b = 0; b < 32; ++b) {
            float qv = qs[d * 33 + b];
            accx[b] += qv * w.x;
            accy[b] += qv * w.y;
        }
    }
    float* t = ws + OFF_T;
    #pragma unroll
    for (int b = 0; b < 32; ++b) {
        float2 o;
        o.x = accx[b] * 0.125f;
        o.y = accy[b] * 0.125f;
        *(float2*)(t + (size_t)(b * H_ + h) * E_ + 2 * tid) = o;
    }
    if (tid < 32) {
        int b = tid;
        float s = 0.f;
        for (int d = 0; d < 64; ++d) s += qs[d * 33 + b] * bk[64 * h + d];
        ws[OFF_QBK + b * H_ + h] = s * 0.125f;
    }
}

// ---------------------------------------------------------------- K2: fused scores/softmax-partial/u_part
__global__ __launch_bounds__(256) void k_attn_core(const float* __restrict__ x,
                                                   float* __restrict__ ws) {
    const int tile = blockIdx.x;  // 0..NT_-1
    const int b = blockIdx.y;     // 0..31
    const int tid = threadIdx.x;
    const int s0 = tile * STILE;
    const float* t = ws + OFF_T + (size_t)b * H_ * E_;
    const float* xb = x + (size_t)(b * L_ + 1 + s0) * E_;

    __shared__ float xs[2][STILE * 33];  // ph1: [s][e-chunk] pad33 ; ph2: [s-chunk][1028]
    __shared__ float ts[2][EC * 17];     // [e][h] pad17
    __shared__ float wl[STILE * 17];     // [s][h] pad17
    __shared__ float red[256];
    __shared__ float msh[16];

    const int sgrp = tid & 63;
    const int hgrp = tid >> 6;  // 0..3, wave-uniform
    const int hq = 4 * hgrp;

    // ---------------- phase 1: scores ----------------
    float4 xr[8];
    float tr[2];
    float acc[4][4];
    #pragma unroll
    for (int i = 0; i < 4; ++i)
        #pragma unroll
        for (int jx = 0; jx < 4; ++jx) acc[i][jx] = 0.f;

    // chunk 0 load
    {
        int ec = 0;
        #pragma unroll
        for (int k = 0; k < 8; ++k) {
            int idx4 = k * 256 + tid;
            int s = idx4 >> 3, e4 = idx4 & 7;
            xr[k] = *(const float4*)(xb + (size_t)s * E_ + ec + 4 * e4);
        }
        #pragma unroll
        for (int k = 0; k < 2; ++k) {
            int idx = k * 256 + tid;
            int hh = idx >> 5, e = idx & 31;
            tr[k] = t[hh * E_ + ec + e];
        }
        #pragma unroll
        for (int k = 0; k < 8; ++k) {
            int idx4 = k * 256 + tid;
            int s = idx4 >> 3, e4 = idx4 & 7;
            float* p = &xs[0][s * 33 + 4 * e4];
            p[0] = xr[k].x; p[1] = xr[k].y; p[2] = xr[k].z; p[3] = xr[k].w;
        }
        #pragma unroll
        for (int k = 0; k < 2; ++k) {
            int idx = k * 256 + tid;
            int hh = idx >> 5, e = idx & 31;
            ts[0][e * 17 + hh] = tr[k];
        }
    }

    for (int c = 0; c < NCH1; ++c) {
        __syncthreads();
        if (c + 1 < NCH1) {
            int ec = (c + 1) * EC;
            #pragma unroll
            for (int k = 0; k < 8; ++k) {
                int idx4 = k * 256 + tid;
                int s = idx4 >> 3, e4 = idx4 & 7;
                xr[k] = *(const float4*)(xb + (size_t)s * E_ + ec + 4 * e4);
            }
            #pragma unroll
            for (int k = 0; k < 2; ++k) {
                int idx = k * 256 + tid;
                int hh = idx >> 5, e = idx & 31;
                tr[k] = t[hh * E_ + ec + e];
            }
        }
        const int buf = c & 1;
        #pragma unroll 8
        for (int e = 0; e < EC; ++e) {
            const float* tsb = &ts[buf][e * 17 + hq];
            float t0 = tsb[0], t1 = tsb[1], t2 = tsb[2], t3 = tsb[3];
            float x0 = xs[buf][(sgrp + 0) * 33 + e];
            float x1 = xs[buf][(sgrp + 64) * 33 + e];
            float x2 = xs[buf][(sgrp + 128) * 33 + e];
            float x3 = xs[buf][(sgrp + 192) * 33 + e];
            acc[0][0] += t0 * x0; acc[0][1] += t0 * x1; acc[0][2] += t0 * x2; acc[0][3] += t0 * x3;
            acc[1][0] += t1 * x0; acc[1][1] += t1 * x1; acc[1][2] += t1 * x2; acc[1][3] += t1 * x3;
            acc[2][0] += t2 * x0; acc[2][1] += t2 * x1; acc[2][2] += t2 * x2; acc[2][3] += t2 * x3;
            acc[3][0] += t3 * x0; acc[3][1] += t3 * x1; acc[3][2] += t3 * x2; acc[3][3] += t3 * x3;
        }
        if (c + 1 < NCH1) {
            const int nbuf = (c + 1) & 1;
            #pragma unroll
            for (int k = 0; k < 8; ++k) {
                int idx4 = k * 256 + tid;
                int s = idx4 >> 3, e4 = idx4 & 7;
                float* p = &xs[nbuf][s * 33 + 4 * e4];
                p[0] = xr[k].x; p[1] = xr[k].y; p[2] = xr[k].z; p[3] = xr[k].w;
            }
            #pragma unroll
            for (int k = 0; k < 2; ++k) {
                int idx = k * 256 + tid;
                int hh = idx >> 5, e = idx & 31;
                ts[nbuf][e * 17 + hh] = tr[k];
            }
        }
    }

    // scores -> wl (add qbk)
    {
        const float* qbk = ws + OFF_QBK + b * H_;
        float qb0 = qbk[hq + 0], qb1 = qbk[hq + 1], qb2 = qbk[hq + 2], qb3 = qbk[hq + 3];
        #pragma unroll
        for (int si = 0; si < 4; ++si) {
            int s = sgrp + 64 * si;
            wl[s * 17 + hq + 0] = acc[0][si] + qb0;
            wl[s * 17 + hq + 1] = acc[1][si] + qb1;
            wl[s * 17 + hq + 2] = acc[2][si] + qb2;
            wl[s * 17 + hq + 3] = acc[3][si] + qb3;
        }
    }
    __syncthreads();

    // ---------------- softmax partials over this tile ----------------
    const int sh = tid & 15;   // h
    const int seg = tid >> 4;  // 0..15, 16 s each
    {
        float m = -1e30f;
        #pragma unroll
        for (int i = 0; i < 16; ++i) m = fmaxf(m, wl[(seg * 16 + i) * 17 + sh]);
        red[seg * 16 + sh] = m;
    }
    __syncthreads();
    if (tid < 16) {
        float mm = -1e30f;
        for (int g = 0; g < 16; ++g) mm = fmaxf(mm, red[g * 16 + tid]);
        msh[tid] = mm;
    }
    __syncthreads();
    {
        float M = msh[sh];
        float ps = 0.f;
        #pragma unroll
        for (int i = 0; i < 16; ++i) {
            int idx = (seg * 16 + i) * 17 + sh;
            float v = __expf(wl[idx] - M);
            wl[idx] = v;
            ps += v;
        }
        __syncthreads();       // red reuse: all reads of red (max) are done
        red[seg * 16 + sh] = ps;
    }
    __syncthreads();
    if (tid < 16) {
        float ss = 0.f;
        for (int g = 0; g < 16; ++g) ss += red[g * 16 + tid];
        ws[OFF_M + (b * NT_ + tile) * H_ + tid] = msh[tid];
        ws[OFF_L + (b * NT_ + tile) * H_ + tid] = ss;
    }

    // ---------------- phase 2: u_part[h][e] = sum_s w[s][h] * x[s][e] ----------------
    float acc2[4][16];
    #pragma unroll
    for (int i = 0; i < 4; ++i)
        #pragma unroll
        for (int jx = 0; jx < 16; ++jx) acc2[i][jx] = 0.f;
    const int egrp = tid & 63;  // e group; h group = hgrp (wave-uniform)

    float4 xr2[8];
    #pragma unroll
    for (int k = 0; k < 8; ++k)
        xr2[k] = *(const float4*)(xb + (size_t)(0 + k) * E_ + 4 * tid);
    // NOTE: first store must wait until all phase-1/softmax readers of xs are done
    __syncthreads();
    #pragma unroll
    for (int k = 0; k < 8; ++k)
        *(float4*)(&xs[0][k * 1028 + 4 * tid]) = xr2[k];

    for (int c = 0; c < NCH2; ++c) {
        __syncthreads();
        if (c + 1 < NCH2) {
            int sc = (c + 1) * SC;
            #pragma unroll
            for (int k = 0; k < 8; ++k)
                xr2[k] = *(const float4*)(xb + (size_t)(sc + k) * E_ + 4 * tid);
        }
        const int buf = c & 1, sc = c * SC;
        #pragma unroll
        for (int sl = 0; sl < SC; ++sl) {
            const float* wp = &wl[(sc + sl) * 17 + hq];
            float w0 = wp[0], w1 = wp[1], w2 = wp[2], w3 = wp[3];
            #pragma unroll
            for (int ej = 0; ej < 4; ++ej) {
                float4 xv = *(const float4*)(&xs[buf][sl * 1028 + 4 * egrp + 256 * ej]);
                acc2[0][ej * 4 + 0] += w0 * xv.x; acc2[0][ej * 4 + 1] += w0 * xv.y;
                acc2[0][ej * 4 + 2] += w0 * xv.z; acc2[0][ej * 4 + 3] += w0 * xv.w;
                acc2[1][ej * 4 + 0] += w1 * xv.x; acc2[1][ej * 4 + 1] += w1 * xv.y;
                acc2[1][ej * 4 + 2] += w1 * xv.z; acc2[1][ej * 4 + 3] += w1 * xv.w;
                acc2[2][ej * 4 + 0] += w2 * xv.x; acc2[2][ej * 4 + 1] += w2 * xv.y;
                acc2[2][ej * 4 + 2] += w2 * xv.z; acc2[2][ej * 4 + 3] += w2 * xv.w;
                acc2[3][ej * 4 + 0] += w3 * xv.x; acc2[3][ej * 4 + 1] += w3 * xv.y;
                acc2[3][ej * 4 + 2] += w3 * xv.z; acc2[3][ej * 4 + 3] += w3 * xv.w;
            }
        }
        if (c + 1 < NCH2) {
            const int nbuf = (c + 1) & 1;
            #pragma unroll
            for (int k = 0; k < 8; ++k)
                *(float4*)(&xs[nbuf][k * 1028 + 4 * tid]) = xr2[k];
        }
    }

    float* up = ws + OFF_UP + (size_t)((b * NT_ + tile) * H_) * E_;
    #pragma unroll
    for (int hi = 0; hi < 4; ++hi) {
        #pragma unroll
        for (int ej = 0; ej < 4; ++ej) {
            float4 o;
            o.x = acc2[hi][ej * 4 + 0]; o.y = acc2[hi][ej * 4 + 1];
            o.z = acc2[hi][ej * 4 + 2]; o.w = acc2[hi][ej * 4 + 3];
            *(float4*)(up + (size_t)(hq + hi) * E_ + 4 * egrp + 256 * ej) = o;
        }
    }
}

// ---------------------------------------------------------------- K3: combine partial softmax tiles
__global__ __launch_bounds__(256) void k_combine(float* __restrict__ ws) {
    const int b = blockIdx.x, h = blockIdx.y, tid = threadIdx.x;
    float m[NT_], l[NT_], f[NT_];
    float M = -1e30f;
    #pragma unroll
    for (int tg = 0; tg < NT_; ++tg) {
        m[tg] = ws[OFF_M + (b * NT_ + tg) * H_ + h];
        l[tg] = ws[OFF_L + (b * NT_ + tg) * H_ + h];
        M = fmaxf(M, m[tg]);
    }
    float Ls = 0.f;
    #pragma unroll
    for (int tg = 0; tg < NT_; ++tg) {
        f[tg] = __expf(m[tg] - M);
        Ls += f[tg] * l[tg];
    }
    const float inv = 1.f / Ls;
    float4 a = make_float4(0.f, 0.f, 0.f, 0.f);
    #pragma unroll
    for (int tg = 0; tg < NT_; ++tg) {
        float4 v = *(const float4*)(ws + OFF_UP + (size_t)((b * NT_ + tg) * H_ + h) * E_ + 4 * tid);
        a.x += f[tg] * v.x; a.y += f[tg] * v.y; a.z += f[tg] * v.z; a.w += f[tg] * v.w;
    }
    a.x *= inv; a.y *= inv; a.z *= inv; a.w *= inv;
    *(float4*)(ws + OFF_U + (size_t)(b * H_ + h) * E_ + 4 * tid) = a;
}

// ---------------------------------------------------------------- K4a: attn = Wv_h @ u_h + bv
__global__ __launch_bounds__(256) void k_vproj(const float* __restrict__ Wv,
                                               const float* __restrict__ bv,
                                               float* __restrict__ ws) {
    __shared__ float ul[8 * 2 * 1024];  // [b][h-local][e]
    const int bg = blockIdx.x, j0 = blockIdx.y * 128, tid = threadIdx.x;
    const int h0 = j0 >> 6;  // 2 heads per slice
    const float* u = ws + OFF_U;
    #pragma unroll
    for (int k = 0; k < 16; ++k) {
        int idx4 = k * 256 + tid;
        int bb = idx4 >> 9, r4 = idx4 & 511;
        *(float4*)(ul + bb * 2048 + 4 * r4) =
            *(const float4*)(u + (size_t)((bg * 8 + bb) * H_ + h0) * E_ + 4 * r4);
    }
    __syncthreads();
    const int jj = tid & 127, bh = tid >> 7;
    const int j = j0 + jj;
    const int hl = jj >> 6;  // wave-uniform
    float a[4] = {0.f, 0.f, 0.f, 0.f};
    const float4* wrow = (const float4*)(Wv + (size_t)j * E_);
    for (int e4 = 0; e4 < 256; ++e4) {
        float4 w = wrow[e4];
        #pragma unroll
        for (int k = 0; k < 4; ++k) {
            const float* upt = ul + (bh * 4 + k) * 2048 + hl * 1024 + 4 * e4;
            a[k] += w.x * upt[0] + w.y * upt[1] + w.z * upt[2] + w.w * upt[3];
        }
    }
    float bvv = bv[j];
    #pragma unroll
    for (int k = 0; k < 4; ++k)
        ws[OFF_ATTN + (size_t)(bg * 8 + bh * 4 + k) * E_ + j] = a[k] + bvv;
}

// ---------------------------------------------------------------- K4b: y = attn @ Wo^T + bo + cls
__global__ __launch_bounds__(256) void k_oproj(const float* __restrict__ x,
                                               const float* __restrict__ Wo,
                                               const float* __restrict__ bo,
                                               float* __restrict__ ws) {
    __shared__ float al[8 * 1024];
    const int bg = blockIdx.x, j0 = blockIdx.y * 128, tid = threadIdx.x;
    #pragma unroll
    for (int k = 0; k < 8; ++k) {
        int idx4 = k * 256 + tid;
        int bb = idx4 >> 8, e4 = idx4 & 255;
        *(float4*)(al + bb * 1024 + 4 * e4) =
            *(const float4*)(ws + OFF_ATTN + (size_t)(bg * 8 + bb) * E_ + 4 * e4);
    }
    __syncthreads();
    const int jj = tid & 127, bh = tid >> 7;
    const int j = j0 + jj;
    float a0 = 0.f, a1 = 0.f, a2 = 0.f, a3 = 0.f;
    const float4* wrow = (const float4*)(Wo + (size_t)j * E_);
    const float* c0 = al + (bh * 4 + 0) * 1024;
    const float* c1 = al + (bh * 4 + 1) * 1024;
    const float* c2 = al + (bh * 4 + 2) * 1024;
    const float* c3 = al + (bh * 4 + 3) * 1024;
    for (int e4 = 0; e4 < 256; ++e4) {
        float4 w = wrow[e4];
        int e = 4 * e4;
        a0 += w.x * c0[e] + w.y * c0[e + 1] + w.z * c0[e + 2] + w.w * c0[e + 3];
        a1 += w.x * c1[e] + w.y * c1[e + 1] + w.z * c1[e + 2] + w.w * c1[e + 3];
        a2 += w.x * c2[e] + w.y * c2[e + 1] + w.z * c2[e + 2] + w.w * c2[e + 3];
        a3 += w.x * c3[e] + w.y * c3[e + 1] + w.z * c3[e + 2] + w.w * c3[e + 3];
    }
    float bov = bo[j];
    float* y = ws + OFF_Y;
    #pragma unroll
    for (int k = 0; k < 4; ++k) {
        int bb = bg * 8 + bh * 4 + k;
        float av = (k == 0) ? a0 : (k == 1) ? a1 : (k == 2) ? a2 : a3;
        y[(size_t)bb * E_ + j] = av + bov + x[(size_t)bb * L_ * E_ + j];
    }
}

// ---------------------------------------------------------------- K4c: LayerNorm -> out
__global__ __launch_bounds__(256) void k_ln(const float* __restrict__ ws,
                                            const float* __restrict__ g,
                                            const float* __restrict__ be,
                                            float* __restrict__ out) {
    const int b = blockIdx.x, tid = threadIdx.x;
    const float* y = ws + OFF_Y + (size_t)b * E_;
    float4 v = *(const float4*)(y + 4 * tid);
    float s = v.x + v.y + v.z + v.w;
    float s2 = v.x * v.x + v.y * v.y + v.z * v.z + v.w * v.w;
    for (int o = 32; o; o >>= 1) {
        s += __shfl_down(s, o, 64);
        s2 += __shfl_down(s2, o, 64);
    }
    __shared__ float rs[4], rs2[4];
    int w = tid >> 6;
    if ((tid & 63) == 0) { rs[w] = s; rs2[w] = s2; }
    __syncthreads();
    float S = rs[0] + rs[1] + rs[2] + rs[3];
    float S2 = rs2[0] + rs2[1] + rs2[2] + rs2[3];
    float mean = S * (1.f / 1024.f);
    float var = S2 * (1.f / 1024.f) - mean * mean;
    float r = rsqrtf(var + 1e-5f);
    float4 gv = *(const float4*)(g + 4 * tid);
    float4 bb2 = *(const float4*)(be + 4 * tid);
    float4 o;
    o.x = (v.x - mean) * r * gv.x + bb2.x;
    o.y = (v.y - mean) * r * gv.y + bb2.y;
    o.z = (v.z - mean) * r * gv.z + bb2.z;
    o.w = (v.w - mean) * r * gv.w + bb2.w;
    *(float4*)(out + (size_t)b * E_ + 4 * tid) = o;
}

extern "C" void kernel_launch(void* const* d_in, const int* in_sizes, int n_in,
                              void* d_out, int out_size, void* d_ws, size_t ws_size,
                              hipStream_t stream) {
    const float* x  = (const float*)d_in[0];
    const float* Wq = (const float*)d_in[1];
    const float* bq = (const float*)d_in[2];
    const float* Wk = (const float*)d_in[3];
    const float* bk = (const float*)d_in[4];
    const float* Wv = (const float*)d_in[5];
    const float* bv = (const float*)d_in[6];
    const float* Wo = (const float*)d_in[7];
    const float* bo = (const float*)d_in[8];
    const float* g  = (const float*)d_in[9];
    const float* be = (const float*)d_in[10];
    float* ws = (float*)d_ws;
    float* out = (float*)d_out;

    k_qproj<<<dim3(4, 8), 256, 0, stream>>>(x, Wq, bq, ws);
    k_tproj<<<dim3(16), 512, 0, stream>>>(Wk, bk, ws);
    k_attn_core<<<dim3(NT_, B_), 256, 0, stream>>>(x, ws);
    k_combine<<<dim3(B_, H_), 256, 0, stream>>>(ws);
    k_vproj<<<dim3(4, 8), 256, 0, stream>>>(Wv, bv, ws);
    k_oproj<<<dim3(4, 8), 256, 0, stream>>>(x, Wo, bo, ws);
    k_ln<<<dim3(B_), 256, 0, stream>>>(ws, g, be, out);
}

// Round 2
// 512.811 us; speedup vs baseline: 1.3285x; 1.3285x over previous
//
#include <hip/hip_runtime.h>
#include <math.h>

#define B_ 32
#define L_ 2049
#define E_ 1024
#define H_ 16
#define NT_ 8
#define STILE 256
#define EC 32

// workspace layout (float offsets) — identical footprint to round 1 (known-safe)
#define OFF_Q     0
#define OFF_T     (OFF_Q + B_*E_)
#define OFF_QBK   (OFF_T + B_*H_*E_)
#define OFF_M     (OFF_QBK + B_*H_)
#define OFF_L     (OFF_M + B_*NT_*H_)
#define OFF_U     (OFF_L + B_*NT_*H_)
#define OFF_ATTN  (OFF_U + B_*H_*E_)
#define OFF_Y     (OFF_ATTN + B_*E_)
#define OFF_UP    (OFF_Y + B_*E_)

// ---------------------------------------------------------------- generic 32xE GEMM:
// C[b][j] = sum_k A[b*As + kbase + k] * W[j][k] + bias[j] (+ resid[b*Rs + j])
// mode 1 (vproj): kbase = (j>>6)*1024 (per-head slice of u). Grid: 512 blocks, j-tile=2.
__global__ __launch_bounds__(256) void k_gemm32(const float* __restrict__ A, long long As, int mode,
                                                const float* __restrict__ W,
                                                const float* __restrict__ bias,
                                                const float* __restrict__ resid, long long Rs,
                                                float* __restrict__ C) {
    __shared__ float wls[2 * 1056];  // 2 swizzled W rows
    const int j0 = blockIdx.x * 2, tid = threadIdx.x;
    #pragma unroll
    for (int k = 0; k < 2; ++k) {
        int idx4 = k * 256 + tid;
        int row = idx4 >> 8, c4 = idx4 & 255;
        float4 v = *(const float4*)(W + (size_t)(j0 + row) * E_ + 4 * c4);
        *(float4*)&wls[row * 1056 + 4 * c4 + ((c4 >> 5) << 2)] = v;  // swizzle: k + (k>>7)*4
    }
    __syncthreads();
    const int bb = tid >> 3, kseg = tid & 7;
    const long long kbase = (mode == 1) ? (long long)(j0 >> 6) * E_ : 0;
    const float* arow = A + (size_t)bb * As + kbase + kseg * 128;
    float a0 = 0.f, a1 = 0.f;
    #pragma unroll 4
    for (int i = 0; i < 32; ++i) {
        float4 av = *(const float4*)(arow + 4 * i);
        const float* wb = &wls[kseg * 132 + 4 * i];
        float4 w0 = *(const float4*)(wb);
        float4 w1 = *(const float4*)(wb + 1056);
        a0 += av.x * w0.x + av.y * w0.y + av.z * w0.z + av.w * w0.w;
        a1 += av.x * w1.x + av.y * w1.y + av.z * w1.z + av.w * w1.w;
    }
    #pragma unroll
    for (int off = 4; off; off >>= 1) {
        a0 += __shfl_down(a0, off, 8);
        a1 += __shfl_down(a1, off, 8);
    }
    if (kseg == 0) {
        float r0 = a0 + bias[j0], r1 = a1 + bias[j0 + 1];
        if (resid) {
            r0 += resid[(size_t)bb * Rs + j0];
            r1 += resid[(size_t)bb * Rs + j0 + 1];
        }
        C[(size_t)bb * E_ + j0] = r0;
        C[(size_t)bb * E_ + j0 + 1] = r1;
    }
}

// ---------------------------------------------------------------- t = 0.125*q_h@Wk_h ; qbk
// grid (16 h, 16 e-tiles of 64), 256 thr
__global__ __launch_bounds__(256) void k_tproj(const float* __restrict__ Wk,
                                               const float* __restrict__ bk,
                                               float* __restrict__ ws) {
    __shared__ float qs[64 * 33];   // [d][b]
    __shared__ float wls[64 * 68];  // [d][e] padded/aligned
    const int h = blockIdx.x, e0 = blockIdx.y * 64, tid = threadIdx.x;
    const float* q = ws + OFF_Q;
    #pragma unroll
    for (int k = 0; k < 8; ++k) {
        int idx = k * 256 + tid;
        int b = idx >> 6, d = idx & 63;
        qs[d * 33 + b] = q[(size_t)b * E_ + 64 * h + d];
    }
    #pragma unroll
    for (int k = 0; k < 4; ++k) {
        int idx4 = k * 256 + tid;
        int d = idx4 >> 4, c4 = idx4 & 15;
        float4 v = *(const float4*)(Wk + (size_t)(64 * h + d) * E_ + e0 + 4 * c4);
        *(float4*)&wls[d * 68 + 4 * c4] = v;
    }
    __syncthreads();
    const int el = tid & 63, bq8 = tid >> 6;
    float acc[8];
    #pragma unroll
    for (int i = 0; i < 8; ++i) acc[i] = 0.f;
    for (int d = 0; d < 64; ++d) {
        float wv = wls[d * 68 + el];
        #pragma unroll
        for (int i = 0; i < 8; ++i) acc[i] += qs[d * 33 + (bq8 * 8 + i)] * wv;
    }
    float* t = ws + OFF_T;
    #pragma unroll
    for (int i = 0; i < 8; ++i)
        t[((size_t)(bq8 * 8 + i) * H_ + h) * E_ + e0 + el] = acc[i] * 0.125f;
    if (e0 == 0 && tid < 32) {
        float s = 0.f;
        for (int d = 0; d < 64; ++d) s += qs[d * 33 + tid] * bk[64 * h + d];
        ws[OFF_QBK + tid * H_ + h] = s * 0.125f;
    }
}

// ---------------------------------------------------------------- fused scores/softmax/u_part
// 512 threads (8 waves). Phase 1: wave w owns e-quad 4w of each 32-e chunk, all 16 heads,
// lane owns 4 s. Phase 2: wave pair (w, w+4) owns head-quad w&3, splits s rows.
__global__ __launch_bounds__(512) void k_attn_core(const float* __restrict__ x,
                                                   float* __restrict__ ws) {
    const int tile = blockIdx.x, b = blockIdx.y, tid = threadIdx.x;
    const int s0 = tile * STILE;
    const float* tmat = ws + OFF_T + (size_t)b * H_ * E_;
    const float* xb = x + (size_t)(b * L_ + 1 + s0) * E_;

    __shared__ float xs[18432];  // ph1: 2 bufs of 256x36 ; ph2: 2 bufs of 8x1028 ; planes 4x4352
    __shared__ float ts[1152];   // 2 bufs of 16x36
    __shared__ float wl[STILE * 20];
    __shared__ float red[512];
    __shared__ float msh[16];

    const int lane = tid & 63;
    const int w = tid >> 6;

    // ================= phase 1: scores[h][s] = sum_e t[h][e]*x[s][e] =================
    float acc[16][4];
    #pragma unroll
    for (int hh = 0; hh < 16; ++hh)
        #pragma unroll
        for (int si = 0; si < 4; ++si) acc[hh][si] = 0.f;

    float4 xr[4];
    float tr;
    const int th = tid >> 5, te = tid & 31;
    {
        #pragma unroll
        for (int k = 0; k < 4; ++k) {
            int idx4 = k * 512 + tid, s = idx4 >> 3, e4 = idx4 & 7;
            xr[k] = *(const float4*)(xb + (size_t)s * E_ + 4 * e4);
        }
        tr = tmat[th * E_ + te];
        #pragma unroll
        for (int k = 0; k < 4; ++k) {
            int idx4 = k * 512 + tid, s = idx4 >> 3, e4 = idx4 & 7;
            *(float4*)&xs[s * 36 + 4 * e4] = xr[k];
        }
        ts[th * 36 + te] = tr;
    }
    for (int c = 0; c < 32; ++c) {
        __syncthreads();
        if (c + 1 < 32) {
            int ec = (c + 1) * EC;
            #pragma unroll
            for (int k = 0; k < 4; ++k) {
                int idx4 = k * 512 + tid, s = idx4 >> 3, e4 = idx4 & 7;
                xr[k] = *(const float4*)(xb + (size_t)s * E_ + ec + 4 * e4);
            }
            tr = tmat[th * E_ + ec + te];
        }
        const int bx = (c & 1) * 9216, bt = (c & 1) * 576;
        float4 xv[4];
        #pragma unroll
        for (int si = 0; si < 4; ++si)
            xv[si] = *(const float4*)&xs[bx + (lane + 64 * si) * 36 + 4 * w];
        #pragma unroll
        for (int hb = 0; hb < 4; ++hb) {
            float4 t0 = *(const float4*)&ts[bt + (4 * hb + 0) * 36 + 4 * w];
            float4 t1 = *(const float4*)&ts[bt + (4 * hb + 1) * 36 + 4 * w];
            float4 t2 = *(const float4*)&ts[bt + (4 * hb + 2) * 36 + 4 * w];
            float4 t3 = *(const float4*)&ts[bt + (4 * hb + 3) * 36 + 4 * w];
            #pragma unroll
            for (int si = 0; si < 4; ++si) {
                acc[4 * hb + 0][si] += t0.x * xv[si].x + t0.y * xv[si].y + t0.z * xv[si].z + t0.w * xv[si].w;
                acc[4 * hb + 1][si] += t1.x * xv[si].x + t1.y * xv[si].y + t1.z * xv[si].z + t1.w * xv[si].w;
                acc[4 * hb + 2][si] += t2.x * xv[si].x + t2.y * xv[si].y + t2.z * xv[si].z + t2.w * xv[si].w;
                acc[4 * hb + 3][si] += t3.x * xv[si].x + t3.y * xv[si].y + t3.z * xv[si].z + t3.w * xv[si].w;
            }
        }
        if (c + 1 < 32) {
            const int nx = ((c + 1) & 1) * 9216, nt = ((c + 1) & 1) * 576;
            #pragma unroll
            for (int k = 0; k < 4; ++k) {
                int idx4 = k * 512 + tid, s = idx4 >> 3, e4 = idx4 & 7;
                *(float4*)&xs[nx + s * 36 + 4 * e4] = xr[k];
            }
            ts[nt + th * 36 + te] = tr;
        }
    }
    __syncthreads();
    // -------- cross-wave e-slice reduction (tree into wave 0), planes reuse xs --------
    if (w >= 4) {
        float* pl = xs + (w - 4) * 4352;
        #pragma unroll
        for (int hh = 0; hh < 16; ++hh)
            #pragma unroll
            for (int si = 0; si < 4; ++si) pl[(lane + 64 * si) * 17 + hh] = acc[hh][si];
    }
    __syncthreads();
    if (w < 4) {
        const float* pl = xs + w * 4352;
        #pragma unroll
        for (int hh = 0; hh < 16; ++hh)
            #pragma unroll
            for (int si = 0; si < 4; ++si) acc[hh][si] += pl[(lane + 64 * si) * 17 + hh];
    }
    __syncthreads();
    if (w == 2 || w == 3) {
        float* pl = xs + (w - 2) * 4352;
        #pragma unroll
        for (int hh = 0; hh < 16; ++hh)
            #pragma unroll
            for (int si = 0; si < 4; ++si) pl[(lane + 64 * si) * 17 + hh] = acc[hh][si];
    }
    __syncthreads();
    if (w < 2) {
        const float* pl = xs + w * 4352;
        #pragma unroll
        for (int hh = 0; hh < 16; ++hh)
            #pragma unroll
            for (int si = 0; si < 4; ++si) acc[hh][si] += pl[(lane + 64 * si) * 17 + hh];
    }
    __syncthreads();
    if (w == 1) {
        float* pl = xs;
        #pragma unroll
        for (int hh = 0; hh < 16; ++hh)
            #pragma unroll
            for (int si = 0; si < 4; ++si) pl[(lane + 64 * si) * 17 + hh] = acc[hh][si];
    }
    __syncthreads();
    if (w == 0) {
        const float* pl = xs;
        const float* qbkp = ws + OFF_QBK + b * H_;
        #pragma unroll
        for (int hh = 0; hh < 16; ++hh) {
            float qb = qbkp[hh];
            #pragma unroll
            for (int si = 0; si < 4; ++si)
                wl[(lane + 64 * si) * 20 + hh] = acc[hh][si] + pl[(lane + 64 * si) * 17 + hh] + qb;
        }
    }
    __syncthreads();

    // ================= softmax partials over the tile =================
    const int sh = tid & 15, seg = tid >> 4;  // 32 segments x 8 s
    {
        float m = -1e30f;
        #pragma unroll
        for (int i = 0; i < 8; ++i) m = fmaxf(m, wl[(seg * 8 + i) * 20 + sh]);
        red[seg * 16 + sh] = m;
    }
    __syncthreads();
    if (tid < 16) {
        float mm = -1e30f;
        for (int g = 0; g < 32; ++g) mm = fmaxf(mm, red[g * 16 + tid]);
        msh[tid] = mm;
    }
    __syncthreads();
    {
        float M = msh[sh];
        float ps = 0.f;
        #pragma unroll
        for (int i = 0; i < 8; ++i) {
            int idx = (seg * 8 + i) * 20 + sh;
            float v = __expf(wl[idx] - M);
            wl[idx] = v;
            ps += v;
        }
        __syncthreads();
        red[seg * 16 + sh] = ps;
    }
    __syncthreads();
    if (tid < 16) {
        float ss = 0.f;
        for (int g = 0; g < 32; ++g) ss += red[g * 16 + tid];
        ws[OFF_M + (b * NT_ + tile) * H_ + tid] = msh[tid];
        ws[OFF_L + (b * NT_ + tile) * H_ + tid] = ss;
    }

    // ================= phase 2: u_part[h][e] = sum_s w[s][h]*x[s][e] =================
    float acc2[4][16];
    #pragma unroll
    for (int i = 0; i < 4; ++i)
        #pragma unroll
        for (int j = 0; j < 16; ++j) acc2[i][j] = 0.f;
    const int hq = 4 * (w & 3), rbase = 4 * (w >> 2);

    float4 xr2[4];
    #pragma unroll
    for (int k = 0; k < 4; ++k) {
        int idx4 = k * 512 + tid, r = idx4 >> 8, c4 = idx4 & 255;
        xr2[k] = *(const float4*)(xb + (size_t)r * E_ + 4 * c4);
    }
    __syncthreads();  // all phase-1/plane readers of xs done
    #pragma unroll
    for (int k = 0; k < 4; ++k) {
        int idx4 = k * 512 + tid, r = idx4 >> 8, c4 = idx4 & 255;
        *(float4*)&xs[r * 1028 + 4 * c4] = xr2[k];
    }
    for (int c = 0; c < 32; ++c) {
        __syncthreads();
        if (c + 1 < 32) {
            int sc = (c + 1) * 8;
            #pragma unroll
            for (int k = 0; k < 4; ++k) {
                int idx4 = k * 512 + tid, r = idx4 >> 8, c4 = idx4 & 255;
                xr2[k] = *(const float4*)(xb + (size_t)(sc + r) * E_ + 4 * c4);
            }
        }
        const int base = (c & 1) * 8224;
        #pragma unroll
        for (int rl = 0; rl < 4; ++rl) {
            const int r = rbase + rl;
            float4 wv = *(const float4*)&wl[(c * 8 + r) * 20 + hq];
            #pragma unroll
            for (int ej = 0; ej < 4; ++ej) {
                float4 xv = *(const float4*)&xs[base + r * 1028 + 4 * lane + 256 * ej];
                acc2[0][4 * ej + 0] += wv.x * xv.x; acc2[0][4 * ej + 1] += wv.x * xv.y;
                acc2[0][4 * ej + 2] += wv.x * xv.z; acc2[0][4 * ej + 3] += wv.x * xv.w;
                acc2[1][4 * ej + 0] += wv.y * xv.x; acc2[1][4 * ej + 1] += wv.y * xv.y;
                acc2[1][4 * ej + 2] += wv.y * xv.z; acc2[1][4 * ej + 3] += wv.y * xv.w;
                acc2[2][4 * ej + 0] += wv.z * xv.x; acc2[2][4 * ej + 1] += wv.z * xv.y;
                acc2[2][4 * ej + 2] += wv.z * xv.z; acc2[2][4 * ej + 3] += wv.z * xv.w;
                acc2[3][4 * ej + 0] += wv.w * xv.x; acc2[3][4 * ej + 1] += wv.w * xv.y;
                acc2[3][4 * ej + 2] += wv.w * xv.z; acc2[3][4 * ej + 3] += wv.w * xv.w;
            }
        }
        if (c + 1 < 32) {
            const int nb = ((c + 1) & 1) * 8224;
            #pragma unroll
            for (int k = 0; k < 4; ++k) {
                int idx4 = k * 512 + tid, r = idx4 >> 8, c4 = idx4 & 255;
                *(float4*)&xs[nb + r * 1028 + 4 * c4] = xr2[k];
            }
        }
    }
    __syncthreads();
    // -------- combine wave pairs, write UP --------
    if (w >= 4) {
        const int qd = w & 3;
        #pragma unroll
        for (int hl = 0; hl < 4; ++hl)
            #pragma unroll
            for (int ej = 0; ej < 4; ++ej) {
                float4 o = make_float4(acc2[hl][4 * ej + 0], acc2[hl][4 * ej + 1],
                                       acc2[hl][4 * ej + 2], acc2[hl][4 * ej + 3]);
                *(float4*)&xs[qd * 4352 + hl * 1024 + 4 * lane + 256 * ej] = o;
            }
    }
    __syncthreads();
    if (w < 4) {
        float* up = ws + OFF_UP + (size_t)((b * NT_ + tile) * H_) * E_;
        #pragma unroll
        for (int hl = 0; hl < 4; ++hl)
            #pragma unroll
            for (int ej = 0; ej < 4; ++ej) {
                float4 pv = *(const float4*)&xs[w * 4352 + hl * 1024 + 4 * lane + 256 * ej];
                float4 o = make_float4(acc2[hl][4 * ej + 0] + pv.x, acc2[hl][4 * ej + 1] + pv.y,
                                       acc2[hl][4 * ej + 2] + pv.z, acc2[hl][4 * ej + 3] + pv.w);
                *(float4*)(up + (size_t)(hq + hl) * E_ + 4 * lane + 256 * ej) = o;
            }
    }
}

// ---------------------------------------------------------------- combine partial tiles
__global__ __launch_bounds__(256) void k_combine(float* __restrict__ ws) {
    const int b = blockIdx.x, h = blockIdx.y, tid = threadIdx.x;
    float m[NT_], l[NT_], f[NT_];
    float M = -1e30f;
    #pragma unroll
    for (int tg = 0; tg < NT_; ++tg) {
        m[tg] = ws[OFF_M + (b * NT_ + tg) * H_ + h];
        l[tg] = ws[OFF_L + (b * NT_ + tg) * H_ + h];
        M = fmaxf(M, m[tg]);
    }
    float Ls = 0.f;
    #pragma unroll
    for (int tg = 0; tg < NT_; ++tg) {
        f[tg] = __expf(m[tg] - M);
        Ls += f[tg] * l[tg];
    }
    const float inv = 1.f / Ls;
    float4 a = make_float4(0.f, 0.f, 0.f, 0.f);
    #pragma unroll
    for (int tg = 0; tg < NT_; ++tg) {
        float4 v = *(const float4*)(ws + OFF_UP + (size_t)((b * NT_ + tg) * H_ + h) * E_ + 4 * tid);
        a.x += f[tg] * v.x; a.y += f[tg] * v.y; a.z += f[tg] * v.z; a.w += f[tg] * v.w;
    }
    a.x *= inv; a.y *= inv; a.z *= inv; a.w *= inv;
    *(float4*)(ws + OFF_U + (size_t)(b * H_ + h) * E_ + 4 * tid) = a;
}

// ---------------------------------------------------------------- LayerNorm -> out
__global__ __launch_bounds__(256) void k_ln(const float* __restrict__ ws,
                                            const float* __restrict__ g,
                                            const float* __restrict__ be,
                                            float* __restrict__ out) {
    const int b = blockIdx.x, tid = threadIdx.x;
    const float* y = ws + OFF_Y + (size_t)b * E_;
    float4 v = *(const float4*)(y + 4 * tid);
    float s = v.x + v.y + v.z + v.w;
    float s2 = v.x * v.x + v.y * v.y + v.z * v.z + v.w * v.w;
    for (int o = 32; o; o >>= 1) {
        s += __shfl_down(s, o, 64);
        s2 += __shfl_down(s2, o, 64);
    }
    __shared__ float rs[4], rs2[4];
    int ww = tid >> 6;
    if ((tid & 63) == 0) { rs[ww] = s; rs2[ww] = s2; }
    __syncthreads();
    float S = rs[0] + rs[1] + rs[2] + rs[3];
    float S2 = rs2[0] + rs2[1] + rs2[2] + rs2[3];
    float mean = S * (1.f / 1024.f);
    float var = S2 * (1.f / 1024.f) - mean * mean;
    float r = rsqrtf(var + 1e-5f);
    float4 gv = *(const float4*)(g + 4 * tid);
    float4 bb2 = *(const float4*)(be + 4 * tid);
    float4 o;
    o.x = (v.x - mean) * r * gv.x + bb2.x;
    o.y = (v.y - mean) * r * gv.y + bb2.y;
    o.z = (v.z - mean) * r * gv.z + bb2.z;
    o.w = (v.w - mean) * r * gv.w + bb2.w;
    *(float4*)(out + (size_t)b * E_ + 4 * tid) = o;
}

extern "C" void kernel_launch(void* const* d_in, const int* in_sizes, int n_in,
                              void* d_out, int out_size, void* d_ws, size_t ws_size,
                              hipStream_t stream) {
    const float* x  = (const float*)d_in[0];
    const float* Wq = (const float*)d_in[1];
    const float* bq = (const float*)d_in[2];
    const float* Wk = (const float*)d_in[3];
    const float* bk = (const float*)d_in[4];
    const float* Wv = (const float*)d_in[5];
    const float* bv = (const float*)d_in[6];
    const float* Wo = (const float*)d_in[7];
    const float* bo = (const float*)d_in[8];
    const float* g  = (const float*)d_in[9];
    const float* be = (const float*)d_in[10];
    float* ws = (float*)d_ws;
    float* out = (float*)d_out;

    // q = cls @ Wq^T + bq
    k_gemm32<<<512, 256, 0, stream>>>(x, (long long)L_ * E_, 0, Wq, bq, nullptr, 0, ws + OFF_Q);
    // t = 0.125 * q_h @ Wk_h ; qbk
    k_tproj<<<dim3(16, 16), 256, 0, stream>>>(Wk, bk, ws);
    // fused attention core
    k_attn_core<<<dim3(NT_, B_), 512, 0, stream>>>(x, ws);
    // combine softmax tiles
    k_combine<<<dim3(B_, H_), 256, 0, stream>>>(ws);
    // attn = Wv_h @ u_h + bv   (per-head K slice of u)
    k_gemm32<<<512, 256, 0, stream>>>(ws + OFF_U, (long long)H_ * E_, 1, Wv, bv, nullptr, 0, ws + OFF_ATTN);
    // y = attn @ Wo^T + bo + cls
    k_gemm32<<<512, 256, 0, stream>>>(ws + OFF_ATTN, (long long)E_, 0, Wo, bo, x, (long long)L_ * E_, ws + OFF_Y);
    // LayerNorm
    k_ln<<<B_, 256, 0, stream>>>(ws, g, be, out);
}